// Round 7
// baseline (1534.606 us; speedup 1.0000x reference)
//
#include <hip/hip_runtime.h>
#include <math.h>

#define NL 2
#define KK 3
#define HIDD 64
#define OUTD 32
#define NB 8
#define NN 10000
#define NE 160000
#define ROWS 80000            // NB*NN;  permuted row index = n*8 + b
#define WSTRIDE (128*HIDD)    // 8192 floats per W[l,d,k]

typedef __attribute__((ext_vector_type(8))) short bf16x8;
typedef __attribute__((ext_vector_type(4))) float f32x4;

__device__ __forceinline__ ushort f2b(float x) {
    union { float f; unsigned u; } v; v.f = x;
    unsigned r = (v.u + 0x7fff + ((v.u >> 16) & 1)) >> 16;
    return (ushort)r;
}
__device__ __forceinline__ float b2f(ushort u) {
    union { unsigned u; float f; } v; v.u = (unsigned)u << 16;
    return v.f;
}

// ---------------- setup ----------------
__global__ void zero_kernel(int* p, long n) {
    long t = (long)blockIdx.x * blockDim.x + threadIdx.x;
    if (t < n) p[t] = 0;
}

__global__ void deg_cnt_kernel(const float* __restrict__ w, const int* __restrict__ src,
                               const int* __restrict__ dst, float* deg_out, float* deg_in,
                               int* cnt_f, int* cnt_r) {
    int e = blockIdx.x * blockDim.x + threadIdx.x;
    if (e >= NE) return;
    int s = src[e], d = dst[e];
    float we = w[e];
    atomicAdd(&deg_out[s], we);
    atomicAdd(&deg_in[d], we);
    atomicAdd(&cnt_f[d], 1);
    atomicAdd(&cnt_r[s], 1);
}

__global__ void scan_kernel(const int* __restrict__ cnt, int* __restrict__ off) {
    __shared__ int part[256];
    const int CH = (NN + 255) / 256;
    int t = threadIdx.x;
    int s = 0;
    for (int i = 0; i < CH; ++i) {
        int idx = t * CH + i;
        if (idx < NN) s += cnt[idx];
    }
    part[t] = s;
    __syncthreads();
    if (t == 0) {
        int run = 0;
        for (int i = 0; i < 256; ++i) { int v = part[i]; part[i] = run; run += v; }
        off[NN] = run;
    }
    __syncthreads();
    int run = part[t];
    for (int i = 0; i < CH; ++i) {
        int idx = t * CH + i;
        if (idx < NN) { off[idx] = run; run += cnt[idx]; }
    }
}

__global__ void copy_pos_kernel(const int* __restrict__ off_f, const int* __restrict__ off_r,
                                int* pos_f, int* pos_r) {
    int t = blockIdx.x * blockDim.x + threadIdx.x;
    if (t < NN) { pos_f[t] = off_f[t]; pos_r[t] = off_r[t]; }
}

__global__ void fill_kernel(const float* __restrict__ w, const int* __restrict__ src,
                            const int* __restrict__ dst, const float* __restrict__ deg_out,
                            const float* __restrict__ deg_in,
                            int* pos_f, int* pos_r,
                            int* col_f, float* w_f, int* col_r, float* w_r) {
    int e = blockIdx.x * blockDim.x + threadIdx.x;
    if (e >= NE) return;
    int s = src[e], d = dst[e];
    float we = w[e];
    float dgo = deg_out[s]; dgo = (dgo > 0.f) ? dgo : 1.f;
    float dgi = deg_in[d];  dgi = (dgi > 0.f) ? dgi : 1.f;
    int pf = atomicAdd(&pos_f[d], 1);
    col_f[pf] = s; w_f[pf] = we / dgo;
    int pr = atomicAdd(&pos_r[s], 1);
    col_r[pr] = d; w_r[pr] = we / dgi;
}

// ---------------- converts ----------------
// W[l][d][k][f:128][o:64] fp32 -> Wt[l][g][d][k][o:64][f:128] bf16 (k0 dir-pair folded)
__global__ void convW_kernel(const float* __restrict__ Wz, const float* __restrict__ Wr,
                             const float* __restrict__ Wh, ushort* __restrict__ Wt) {
    int t = blockIdx.x * 256 + threadIdx.x;   // over 589824
    if (t >= 2 * 3 * 2 * 3 * 64 * 128) return;
    int f = t & 127;
    int r1 = t >> 7;
    int o = r1 & 63;
    int r2 = r1 >> 6;
    int k = r2 % 3;
    int r3 = r2 / 3;
    int d = r3 & 1;
    int r4 = r3 >> 1;
    int g = r4 % 3;
    int l = r4 / 3;
    const float* W = (g == 0) ? Wz : (g == 1) ? Wr : Wh;
    float v = W[(((long)(l * 2 + d) * 3 + k) * 128 + f) * 64 + o];
    if (k == 0 && d == 0)
        v += W[(((long)(l * 2 + 1) * 3 + 0) * 128 + f) * 64 + o];
    Wt[t] = f2b(v);
}

// [B][N][64] fp32 -> xh[(n*8+b)*128 + c*64 ..] bf16
__global__ void convX_perm(const float4* __restrict__ in, ushort* __restrict__ xh, int c) {
    long t = (long)blockIdx.x * blockDim.x + threadIdx.x;   // over ROWS*16 float4s
    if (t >= (long)ROWS * 16) return;
    int q = (int)(t & 15);
    long rowin = t >> 4;            // b*NN + n
    int b = (int)(rowin / NN);
    int n = (int)(rowin - (long)b * NN);
    float4 v = in[t];
    ushort4 r;
    r.x = f2b(v.x); r.y = f2b(v.y); r.z = f2b(v.z); r.w = f2b(v.w);
    long orow = (long)n * 8 + b;
    *(ushort4*)&xh[orow * 128 + c * 64 + q * 4] = r;
}

// ---------------- XCD-sliced CSR props ----------------
// bid = n*8 + b  ->  XCD (bid%8) == b under round-robin dispatch: each XCD's
// gather working set is one batch slice (2.56 MB full / 1.28 MB half) < 4 MiB L2.
// 2 waves per block: wave 0 = forward CSR, wave 1 = reverse CSR.
__global__ __launch_bounds__(128) void prop_full(
        const ushort* __restrict__ Xf, const ushort* __restrict__ Xr,
        const ushort* __restrict__ base,
        const int* __restrict__ off_f, const int* __restrict__ col_f,
        const float* __restrict__ w_f,
        const int* __restrict__ off_r, const int* __restrict__ col_r,
        const float* __restrict__ w_r,
        ushort* __restrict__ outf, ushort* __restrict__ outr,
        float alpha, float beta) {
    int bid = blockIdx.x;
    int n = bid >> 3, b = bid & 7;
    int dir  = threadIdx.x >> 6;
    int lane = threadIdx.x & 63;
    const ushort* X; const int* off; const int* col; const float* w; ushort* out;
    if (dir == 0) { X = Xf; off = off_f; col = col_f; w = w_f; out = outf; }
    else          { X = Xr; off = off_r; col = col_r; w = w_r; out = outr; }
    int s = off[n], e = off[n + 1];
    int eo = b * 128 + lane * 2;        // 2 bf16 per lane -> 256B per edge per wave
    float a0 = 0.f, a1 = 0.f;
    int j = s;
    for (; j + 2 <= e; j += 2) {
        int c0 = col[j], c1 = col[j + 1];
        float w0 = w[j], w1 = w[j + 1];
        ushort2 v0 = *(const ushort2*)&X[(long)c0 * 1024 + eo];
        ushort2 v1 = *(const ushort2*)&X[(long)c1 * 1024 + eo];
        a0 = fmaf(b2f(v0.x), w0, a0); a1 = fmaf(b2f(v0.y), w0, a1);
        a0 = fmaf(b2f(v1.x), w1, a0); a1 = fmaf(b2f(v1.y), w1, a1);
    }
    if (j < e) {
        int c = col[j];
        float ww = w[j];
        ushort2 v = *(const ushort2*)&X[(long)c * 1024 + eo];
        a0 = fmaf(b2f(v.x), ww, a0); a1 = fmaf(b2f(v.y), ww, a1);
    }
    long o = (long)n * 1024 + eo;
    a0 *= alpha; a1 *= alpha;
    if (beta != 0.f) {
        ushort2 bb = *(const ushort2*)&base[o];
        a0 = fmaf(beta, b2f(bb.x), a0);
        a1 = fmaf(beta, b2f(bb.y), a1);
    }
    ushort2 r; r.x = f2b(a0); r.y = f2b(a1);
    *(ushort2*)&out[o] = r;
}

// chunk-1 half rows (feats 64..127 within the 128-stride rows)
__global__ __launch_bounds__(128) void prop_half(
        const ushort* __restrict__ Xf, const ushort* __restrict__ Xr,
        const ushort* __restrict__ base,
        const int* __restrict__ off_f, const int* __restrict__ col_f,
        const float* __restrict__ w_f,
        const int* __restrict__ off_r, const int* __restrict__ col_r,
        const float* __restrict__ w_r,
        ushort* __restrict__ outf, ushort* __restrict__ outr,
        float alpha, float beta) {
    int bid = blockIdx.x;
    int n = bid >> 3, b = bid & 7;
    int dir  = threadIdx.x >> 6;
    int lane = threadIdx.x & 63;
    const ushort* X; const int* off; const int* col; const float* w; ushort* out;
    if (dir == 0) { X = Xf; off = off_f; col = col_f; w = w_f; out = outf; }
    else          { X = Xr; off = off_r; col = col_r; w = w_r; out = outr; }
    int s = off[n], e = off[n + 1];
    int eo = b * 128 + 64 + lane;       // 1 bf16 per lane -> 128B per edge per wave
    float a0 = 0.f;
    int j = s;
    for (; j + 2 <= e; j += 2) {
        int c0 = col[j], c1 = col[j + 1];
        float w0 = w[j], w1 = w[j + 1];
        ushort v0 = X[(long)c0 * 1024 + eo];
        ushort v1 = X[(long)c1 * 1024 + eo];
        a0 = fmaf(b2f(v0), w0, a0);
        a0 = fmaf(b2f(v1), w1, a0);
    }
    if (j < e) {
        a0 = fmaf(b2f(X[(long)col[j] * 1024 + eo]), w[j], a0);
    }
    long o = (long)n * 1024 + eo;
    a0 *= alpha;
    if (beta != 0.f) a0 = fmaf(beta, b2f(base[o]), a0);
    out[o] = f2b(a0);
}

// ---------------- MFMA 10-term GEMMs (stride-128 X rows), register-pipelined ----------------
struct GM {
    const ushort* X[10];    // pre-offset by chunk*64; row stride 128
    const ushort* Wa[10];   // pre-offset by chunk*64; row stride 128
    const ushort* Wb[10];
};

#define LOADF(tt, aa, bb)                                                          \
    {                                                                              \
        const ushort* Xp = A.X[tt];                                                \
        const ushort* Wp = gate ? A.Wb[tt] : A.Wa[tt];                             \
        _Pragma("unroll")                                                          \
        for (int ks = 0; ks < 2; ++ks) {                                           \
            _Pragma("unroll")                                                      \
            for (int mi = 0; mi < 2; ++mi)                                         \
                aa[ks][mi] = *(const bf16x8*)&Xp[(grow + mi * 16 + lr) * 128 +     \
                                                 ks * 32 + lk * 8];                \
            _Pragma("unroll")                                                      \
            for (int ni = 0; ni < 4; ++ni)                                         \
                bb[ks][ni] = *(const bf16x8*)&Wp[(ni * 16 + lr) * 128 +            \
                                                 ks * 32 + lk * 8];                \
        }                                                                          \
    }

#define MFMAF(aa, bb)                                                              \
    _Pragma("unroll")                                                              \
    for (int ks = 0; ks < 2; ++ks)                                                 \
        _Pragma("unroll")                                                          \
        for (int mi = 0; mi < 2; ++mi)                                             \
            _Pragma("unroll")                                                      \
            for (int ni = 0; ni < 4; ++ni)                                         \
                acc[mi][ni] = __builtin_amdgcn_mfma_f32_16x16x32_bf16(             \
                    aa[ks][mi], bb[ks][ni], acc[mi][ni], 0, 0, 0);

// dual gate: 64 rows/block, 4 waves (gate x 32-row half)
// gate0 -> Z[row*64+c] = sigmoid; gate1 -> xh[row*128+64+c] = bf16(sigmoid*h)
template<int NT>
__global__ __launch_bounds__(256) void mfma_dual(GM A,
        const float* __restrict__ bzp, const float* __restrict__ brp,
        const float* __restrict__ h,
        float* __restrict__ Z, ushort* __restrict__ xh) {
    int lane = threadIdx.x & 63;
    int wid  = threadIdx.x >> 6;
    int gate = wid >> 1;
    long grow = (long)blockIdx.x * 64 + (long)(wid & 1) * 32;
    int lr = lane & 15;
    int lk = lane >> 4;
    f32x4 acc[2][4];
    #pragma unroll
    for (int i = 0; i < 2; ++i)
        #pragma unroll
        for (int j = 0; j < 4; ++j)
            acc[i][j] = (f32x4){0.f, 0.f, 0.f, 0.f};

    bf16x8 a0[2][2], b0[2][4], a1[2][2], b1[2][4];
    LOADF(0, a0, b0);
    #pragma unroll
    for (int tt = 0; tt < NT; tt += 2) {
        if (tt + 1 < NT) LOADF(tt + 1, a1, b1);
        MFMAF(a0, b0);
        if (tt + 2 < NT) LOADF(tt + 2, a0, b0);
        if (tt + 1 < NT) MFMAF(a1, b1);
    }

    const float* bias = gate ? brp : bzp;
    #pragma unroll
    for (int mi = 0; mi < 2; ++mi) {
        #pragma unroll
        for (int q = 0; q < 4; ++q) {
            long row = grow + mi * 16 + lk * 4 + q;
            int n = (int)(row >> 3), b = (int)(row & 7);
            #pragma unroll
            for (int ni = 0; ni < 4; ++ni) {
                int colc = ni * 16 + lr;
                float v = acc[mi][ni][q] + bias[colc];
                float sg = 1.f / (1.f + expf(-v));
                if (gate == 0) {
                    Z[row * 64 + colc] = sg;
                } else {
                    float hv = h[((long)b * NN + n) * 64 + colc];
                    xh[row * 128 + 64 + colc] = f2b(sg * hv);
                }
            }
        }
    }
}

// single gate (H): 64 rows/block, 2 waves; fused GRU blend epilogue
template<int NT>
__global__ __launch_bounds__(128) void mfma_single(GM A,
        const float* __restrict__ bhp, const float* __restrict__ h,
        const float* __restrict__ Zg,
        float* __restrict__ outF, ushort* __restrict__ xh, int writeF) {
    int lane = threadIdx.x & 63;
    int wid  = threadIdx.x >> 6;
    const int gate = 0;
    long grow = (long)blockIdx.x * 64 + (long)wid * 32;
    int lr = lane & 15;
    int lk = lane >> 4;
    f32x4 acc[2][4];
    #pragma unroll
    for (int i = 0; i < 2; ++i)
        #pragma unroll
        for (int j = 0; j < 4; ++j)
            acc[i][j] = (f32x4){0.f, 0.f, 0.f, 0.f};

    bf16x8 a0[2][2], b0[2][4], a1[2][2], b1[2][4];
    LOADF(0, a0, b0);
    #pragma unroll
    for (int tt = 0; tt < NT; tt += 2) {
        if (tt + 1 < NT) LOADF(tt + 1, a1, b1);
        MFMAF(a0, b0);
        if (tt + 2 < NT) LOADF(tt + 2, a0, b0);
        if (tt + 1 < NT) MFMAF(a1, b1);
    }

    #pragma unroll
    for (int mi = 0; mi < 2; ++mi) {
        #pragma unroll
        for (int q = 0; q < 4; ++q) {
            long row = grow + mi * 16 + lk * 4 + q;
            int n = (int)(row >> 3), b = (int)(row & 7);
            #pragma unroll
            for (int ni = 0; ni < 4; ++ni) {
                int colc = ni * 16 + lr;
                float v = acc[mi][ni][q] + bhp[colc];
                float ht = tanhf(v);
                float z = Zg[row * 64 + colc];
                float hv = h[((long)b * NN + n) * 64 + colc];
                float res = z * hv + (1.f - z) * ht;
                if (writeF) outF[row * 64 + colc] = res;
                else        xh[row * 128 + colc] = f2b(res);
            }
        }
    }
}

// ---------------- final projection 64 -> 32 (permuted input rows) ----------------
__global__ void proj_kernel(const float* __restrict__ last, const float* __restrict__ W,
                            const float* __restrict__ bias, float* __restrict__ out) {
    long t = (long)blockIdx.x * blockDim.x + threadIdx.x;
    if (t >= (long)ROWS * OUTD) return;
    long row = t >> 5;              // n*8 + b
    int  o   = (int)(t & 31);
    int n = (int)(row >> 3), b = (int)(row & 7);
    float acc = bias[o];
    #pragma unroll
    for (int hh = 0; hh < HIDD; ++hh)
        acc = fmaf(last[row * 64 + hh], W[hh * OUTD + o], acc);
    out[((long)b * NN + n) * 32 + o] = acc;
}

extern "C" void kernel_launch(void* const* d_in, const int* in_sizes, int n_in,
                              void* d_out, int out_size, void* d_ws, size_t ws_size,
                              hipStream_t stream) {
    const float* edge_weight = (const float*)d_in[0];
    const float* hidden      = (const float*)d_in[1];
    const float* go_input    = (const float*)d_in[2];
    const float* Wz = (const float*)d_in[3];
    const float* bz = (const float*)d_in[4];
    const float* Wr = (const float*)d_in[5];
    const float* br = (const float*)d_in[6];
    const float* Wh = (const float*)d_in[7];
    const float* bh = (const float*)d_in[8];
    const float* projW = (const float*)d_in[9];
    const float* projb = (const float*)d_in[10];
    const int*   eidx  = (const int*)d_in[11];
    const int* src = eidx;
    const int* dst = eidx + NE;
    float* out = (float*)d_out;

    // ---- workspace ----
    char* p = (char*)d_ws;
    auto alloc = [&](size_t bytes) { char* r = p; p += (bytes + 15) & ~(size_t)15; return r; };
    float* deg_out = (float*)alloc(NN * 4);
    float* deg_in  = (float*)alloc(NN * 4);
    int*   cnt_f   = (int*)alloc(NN * 4);
    int*   cnt_r   = (int*)alloc(NN * 4);
    int*   off_f   = (int*)alloc((NN + 4) * 4);
    int*   off_r   = (int*)alloc((NN + 4) * 4);
    int*   pos_f   = (int*)alloc(NN * 4);
    int*   pos_r   = (int*)alloc(NN * 4);
    int*   col_f   = (int*)alloc(NE * 4);
    float* w_f     = (float*)alloc(NE * 4);
    int*   col_r   = (int*)alloc(NE * 4);
    float* w_r     = (float*)alloc(NE * 4);
    ushort* Wt     = (ushort*)alloc((size_t)2 * 3 * 2 * 3 * 64 * 128 * 2);
    const size_t XB = (size_t)ROWS * 128 * 2;   // 20.48 MB (128-wide bf16)
    ushort* xh  = (ushort*)alloc(XB);
    ushort* Tf1 = (ushort*)alloc(XB);
    ushort* Tf2 = (ushort*)alloc(XB);
    ushort* Tr1 = (ushort*)alloc(XB);
    ushort* Tr2 = (ushort*)alloc(XB);
    float*  Zbuf = (float*)alloc((size_t)ROWS * HIDD * 4);
    if ((size_t)(p - (char*)d_ws) > ws_size) return;

    const int TB = 256;
    const int EGRID = (NE + TB - 1) / TB;

    // ---- CSR build ----
    zero_kernel<<<(4 * NN + TB - 1) / TB, TB, 0, stream>>>((int*)deg_out, 4 * NN);
    deg_cnt_kernel<<<EGRID, TB, 0, stream>>>(edge_weight, src, dst, deg_out, deg_in, cnt_f, cnt_r);
    scan_kernel<<<1, 256, 0, stream>>>(cnt_f, off_f);
    scan_kernel<<<1, 256, 0, stream>>>(cnt_r, off_r);
    copy_pos_kernel<<<(NN + TB - 1) / TB, TB, 0, stream>>>(off_f, off_r, pos_f, pos_r);
    fill_kernel<<<EGRID, TB, 0, stream>>>(edge_weight, src, dst, deg_out, deg_in,
                                          pos_f, pos_r, col_f, w_f, col_r, w_r);

    convW_kernel<<<2304, 256, 0, stream>>>(Wz, Wr, Wh, Wt);
    convX_perm<<<5000, 256, 0, stream>>>((const float4*)go_input, xh, 0);

    auto wt_term = [&](int l, int g, int d, int k, int c) -> const ushort* {
        return Wt + ((((long)((l * 3 + g) * 2 + d) * 3 + k) * 64) * 128) + (long)c * 64;
    };
    const int dd[5]  = {0, 0, 0, 1, 1};
    const int kk2[5] = {0, 1, 2, 1, 2};
    const int PGRID = NN * 8;    // bid = n*8 + b  (XCD slice = batch)

    for (int l = 0; l < NL; ++l) {
        const float* h = hidden + (long)l * ROWS * HIDD;
        convX_perm<<<5000, 256, 0, stream>>>((const float4*)h, xh, 1);

        // xh diffusion (both chunks at once, fwd+rev waves)
        prop_full<<<PGRID, 128, 0, stream>>>(xh, xh, nullptr,
            off_f, col_f, w_f, off_r, col_r, w_r, Tf1, Tr1, 1.f, 0.f);
        prop_full<<<PGRID, 128, 0, stream>>>(Tf1, Tr1, xh,
            off_f, col_f, w_f, off_r, col_r, w_r, Tf2, Tr2, 2.f, -1.f);

        const ushort* xs[5] = {xh, Tf1, Tf2, Tr1, Tr2};
        GM A{};
        for (int i = 0; i < 5; ++i) {
            A.X[i]      = xs[i];
            A.X[5 + i]  = xs[i] + 64;
            A.Wa[i]     = wt_term(l, 0, dd[i], kk2[i], 0);
            A.Wa[5 + i] = wt_term(l, 0, dd[i], kk2[i], 1);
            A.Wb[i]     = wt_term(l, 1, dd[i], kk2[i], 0);
            A.Wb[5 + i] = wt_term(l, 1, dd[i], kk2[i], 1);
        }
        mfma_dual<10><<<ROWS / 64, 256, 0, stream>>>(A, bz + l * HIDD, br + l * HIDD,
                                                     h, Zbuf, xh);

        // rh diffusion into the chunk-1 halves (rh lives in xh chunk1)
        prop_half<<<PGRID, 128, 0, stream>>>(xh, xh, nullptr,
            off_f, col_f, w_f, off_r, col_r, w_r, Tf1, Tr1, 1.f, 0.f);
        prop_half<<<PGRID, 128, 0, stream>>>(Tf1, Tr1, xh,
            off_f, col_f, w_f, off_r, col_r, w_r, Tf2, Tr2, 2.f, -1.f);

        GM Ah{};
        for (int i = 0; i < 5; ++i) {
            Ah.X[i]      = xs[i];
            Ah.X[5 + i]  = xs[i] + 64;
            Ah.Wa[i]     = wt_term(l, 2, dd[i], kk2[i], 0);
            Ah.Wa[5 + i] = wt_term(l, 2, dd[i], kk2[i], 1);
        }
        mfma_single<10><<<ROWS / 64, 128, 0, stream>>>(Ah, bh + l * HIDD, h, Zbuf,
                                                       Zbuf, xh, (l == NL - 1) ? 1 : 0);
    }

    proj_kernel<<<(int)(((long)ROWS * OUTD + TB - 1) / TB), TB, 0, stream>>>(
        Zbuf, projW, projb, out);
}

// Round 8
// 1151.025 us; speedup vs baseline: 1.3333x; 1.3333x over previous
//
#include <hip/hip_runtime.h>
#include <math.h>

#define NL 2
#define KK 3
#define HIDD 64
#define OUTD 32
#define NB 8
#define NN 10000
#define NE 160000
#define ROWS 80000            // NB*NN;  permuted row index = n*8 + b
#define WSTRIDE (128*HIDD)    // 8192 floats per W[l,d,k]

typedef __attribute__((ext_vector_type(8))) short bf16x8;
typedef __attribute__((ext_vector_type(8))) unsigned short u16x8;
typedef __attribute__((ext_vector_type(4))) float f32x4;

__device__ __forceinline__ ushort f2b(float x) {
    union { float f; unsigned u; } v; v.f = x;
    unsigned r = (v.u + 0x7fff + ((v.u >> 16) & 1)) >> 16;
    return (ushort)r;
}
__device__ __forceinline__ float b2f(ushort u) {
    union { unsigned u; float f; } v; v.u = (unsigned)u << 16;
    return v.f;
}

// ---------------- setup ----------------
__global__ void zero_kernel(int* p, long n) {
    long t = (long)blockIdx.x * blockDim.x + threadIdx.x;
    if (t < n) p[t] = 0;
}

__global__ void deg_cnt_kernel(const float* __restrict__ w, const int* __restrict__ src,
                               const int* __restrict__ dst, float* deg_out, float* deg_in,
                               int* cnt_f, int* cnt_r) {
    int e = blockIdx.x * blockDim.x + threadIdx.x;
    if (e >= NE) return;
    int s = src[e], d = dst[e];
    float we = w[e];
    atomicAdd(&deg_out[s], we);
    atomicAdd(&deg_in[d], we);
    atomicAdd(&cnt_f[d], 1);
    atomicAdd(&cnt_r[s], 1);
}

__global__ void scan_kernel(const int* __restrict__ cnt, int* __restrict__ off) {
    __shared__ int part[256];
    const int CH = (NN + 255) / 256;
    int t = threadIdx.x;
    int s = 0;
    for (int i = 0; i < CH; ++i) {
        int idx = t * CH + i;
        if (idx < NN) s += cnt[idx];
    }
    part[t] = s;
    __syncthreads();
    if (t == 0) {
        int run = 0;
        for (int i = 0; i < 256; ++i) { int v = part[i]; part[i] = run; run += v; }
        off[NN] = run;
    }
    __syncthreads();
    int run = part[t];
    for (int i = 0; i < CH; ++i) {
        int idx = t * CH + i;
        if (idx < NN) { off[idx] = run; run += cnt[idx]; }
    }
}

__global__ void copy_pos_kernel(const int* __restrict__ off_f, const int* __restrict__ off_r,
                                int* pos_f, int* pos_r) {
    int t = blockIdx.x * blockDim.x + threadIdx.x;
    if (t < NN) { pos_f[t] = off_f[t]; pos_r[t] = off_r[t]; }
}

__global__ void fill_kernel(const float* __restrict__ w, const int* __restrict__ src,
                            const int* __restrict__ dst, const float* __restrict__ deg_out,
                            const float* __restrict__ deg_in,
                            int* pos_f, int* pos_r,
                            int* col_f, float* w_f, int* col_r, float* w_r) {
    int e = blockIdx.x * blockDim.x + threadIdx.x;
    if (e >= NE) return;
    int s = src[e], d = dst[e];
    float we = w[e];
    float dgo = deg_out[s]; dgo = (dgo > 0.f) ? dgo : 1.f;
    float dgi = deg_in[d];  dgi = (dgi > 0.f) ? dgi : 1.f;
    int pf = atomicAdd(&pos_f[d], 1);
    col_f[pf] = s; w_f[pf] = we / dgo;
    int pr = atomicAdd(&pos_r[s], 1);
    col_r[pr] = d; w_r[pr] = we / dgi;
}

// ---------------- converts ----------------
// W[l][d][k][f:128][o:64] fp32 -> Wt[l][g][d][k][o:64][f:128] bf16 (k0 dir-pair folded)
__global__ void convW_kernel(const float* __restrict__ Wz, const float* __restrict__ Wr,
                             const float* __restrict__ Wh, ushort* __restrict__ Wt) {
    int t = blockIdx.x * 256 + threadIdx.x;   // over 589824
    if (t >= 2 * 3 * 2 * 3 * 64 * 128) return;
    int f = t & 127;
    int r1 = t >> 7;
    int o = r1 & 63;
    int r2 = r1 >> 6;
    int k = r2 % 3;
    int r3 = r2 / 3;
    int d = r3 & 1;
    int r4 = r3 >> 1;
    int g = r4 % 3;
    int l = r4 / 3;
    const float* W = (g == 0) ? Wz : (g == 1) ? Wr : Wh;
    float v = W[(((long)(l * 2 + d) * 3 + k) * 128 + f) * 64 + o];
    if (k == 0 && d == 0)
        v += W[(((long)(l * 2 + 1) * 3 + 0) * 128 + f) * 64 + o];
    Wt[t] = f2b(v);
}

// [B][N][64] fp32 -> xh[(n*8+b)*128 + c*64 ..] bf16
__global__ void convX_perm(const float4* __restrict__ in, ushort* __restrict__ xh, int c) {
    long t = (long)blockIdx.x * blockDim.x + threadIdx.x;   // over ROWS*16 float4s
    if (t >= (long)ROWS * 16) return;
    int q = (int)(t & 15);
    long rowin = t >> 4;            // b*NN + n
    int b = (int)(rowin / NN);
    int n = (int)(rowin - (long)b * NN);
    float4 v = in[t];
    ushort4 r;
    r.x = f2b(v.x); r.y = f2b(v.y); r.z = f2b(v.z); r.w = f2b(v.w);
    long orow = (long)n * 8 + b;
    *(ushort4*)&xh[orow * 128 + c * 64 + q * 4] = r;
}

// ---------------- coalesced CSR props (batch-inner layout, 4-way MLP) ----------------
// full row: 1024 ushorts ([B=8][128]); 128 threads x 16B; blockIdx.y = direction
__global__ __launch_bounds__(128) void prop_full(
        const ushort* __restrict__ Xf, const ushort* __restrict__ Xr,
        const ushort* __restrict__ base,
        const int* __restrict__ off_f, const int* __restrict__ col_f,
        const float* __restrict__ w_f,
        const int* __restrict__ off_r, const int* __restrict__ col_r,
        const float* __restrict__ w_r,
        ushort* __restrict__ outf, ushort* __restrict__ outr,
        float alpha, float beta) {
    int n = blockIdx.x;
    const ushort* X; const int* off; const int* col; const float* w; ushort* out;
    if (blockIdx.y == 0) { X = Xf; off = off_f; col = col_f; w = w_f; out = outf; }
    else                 { X = Xr; off = off_r; col = col_r; w = w_r; out = outr; }
    int t = threadIdx.x;
    int s = off[n], e = off[n + 1];
    float acc[8];
    #pragma unroll
    for (int i = 0; i < 8; ++i) acc[i] = 0.f;
    int j = s;
    for (; j + 4 <= e; j += 4) {
        int c0 = col[j], c1 = col[j + 1], c2 = col[j + 2], c3 = col[j + 3];
        float w0 = w[j], w1 = w[j + 1], w2 = w[j + 2], w3 = w[j + 3];
        u16x8 v0 = *(const u16x8*)&X[(long)c0 * 1024 + t * 8];
        u16x8 v1 = *(const u16x8*)&X[(long)c1 * 1024 + t * 8];
        u16x8 v2 = *(const u16x8*)&X[(long)c2 * 1024 + t * 8];
        u16x8 v3 = *(const u16x8*)&X[(long)c3 * 1024 + t * 8];
        #pragma unroll
        for (int i = 0; i < 8; ++i) acc[i] = fmaf(b2f(v0[i]), w0, acc[i]);
        #pragma unroll
        for (int i = 0; i < 8; ++i) acc[i] = fmaf(b2f(v1[i]), w1, acc[i]);
        #pragma unroll
        for (int i = 0; i < 8; ++i) acc[i] = fmaf(b2f(v2[i]), w2, acc[i]);
        #pragma unroll
        for (int i = 0; i < 8; ++i) acc[i] = fmaf(b2f(v3[i]), w3, acc[i]);
    }
    if (j + 2 <= e) {
        int c0 = col[j], c1 = col[j + 1];
        float w0 = w[j], w1 = w[j + 1];
        u16x8 v0 = *(const u16x8*)&X[(long)c0 * 1024 + t * 8];
        u16x8 v1 = *(const u16x8*)&X[(long)c1 * 1024 + t * 8];
        #pragma unroll
        for (int i = 0; i < 8; ++i) acc[i] = fmaf(b2f(v0[i]), w0, acc[i]);
        #pragma unroll
        for (int i = 0; i < 8; ++i) acc[i] = fmaf(b2f(v1[i]), w1, acc[i]);
        j += 2;
    }
    if (j < e) {
        int c = col[j];
        float ww = w[j];
        u16x8 v = *(const u16x8*)&X[(long)c * 1024 + t * 8];
        #pragma unroll
        for (int i = 0; i < 8; ++i) acc[i] = fmaf(b2f(v[i]), ww, acc[i]);
    }
    long o = (long)n * 1024 + t * 8;
    #pragma unroll
    for (int i = 0; i < 8; ++i) acc[i] *= alpha;
    if (beta != 0.f) {
        u16x8 bb = *(const u16x8*)&base[o];
        #pragma unroll
        for (int i = 0; i < 8; ++i) acc[i] = fmaf(beta, b2f(bb[i]), acc[i]);
    }
    u16x8 r;
    #pragma unroll
    for (int i = 0; i < 8; ++i) r[i] = f2b(acc[i]);
    *(u16x8*)&out[o] = r;
}

// chunk-1 half (feats 64..127 within 128-stride rows); 64 threads x 16B
__global__ __launch_bounds__(64) void prop_half(
        const ushort* __restrict__ Xf, const ushort* __restrict__ Xr,
        const ushort* __restrict__ base,
        const int* __restrict__ off_f, const int* __restrict__ col_f,
        const float* __restrict__ w_f,
        const int* __restrict__ off_r, const int* __restrict__ col_r,
        const float* __restrict__ w_r,
        ushort* __restrict__ outf, ushort* __restrict__ outr,
        float alpha, float beta) {
    int n = blockIdx.x;
    const ushort* X; const int* off; const int* col; const float* w; ushort* out;
    if (blockIdx.y == 0) { X = Xf; off = off_f; col = col_f; w = w_f; out = outf; }
    else                 { X = Xr; off = off_r; col = col_r; w = w_r; out = outr; }
    int t = threadIdx.x;
    int elem = (t >> 3) * 128 + 64 + (t & 7) * 8;   // [b][64 + f8*8]
    int s = off[n], e = off[n + 1];
    float acc[8];
    #pragma unroll
    for (int i = 0; i < 8; ++i) acc[i] = 0.f;
    int j = s;
    for (; j + 4 <= e; j += 4) {
        int c0 = col[j], c1 = col[j + 1], c2 = col[j + 2], c3 = col[j + 3];
        float w0 = w[j], w1 = w[j + 1], w2 = w[j + 2], w3 = w[j + 3];
        u16x8 v0 = *(const u16x8*)&X[(long)c0 * 1024 + elem];
        u16x8 v1 = *(const u16x8*)&X[(long)c1 * 1024 + elem];
        u16x8 v2 = *(const u16x8*)&X[(long)c2 * 1024 + elem];
        u16x8 v3 = *(const u16x8*)&X[(long)c3 * 1024 + elem];
        #pragma unroll
        for (int i = 0; i < 8; ++i) acc[i] = fmaf(b2f(v0[i]), w0, acc[i]);
        #pragma unroll
        for (int i = 0; i < 8; ++i) acc[i] = fmaf(b2f(v1[i]), w1, acc[i]);
        #pragma unroll
        for (int i = 0; i < 8; ++i) acc[i] = fmaf(b2f(v2[i]), w2, acc[i]);
        #pragma unroll
        for (int i = 0; i < 8; ++i) acc[i] = fmaf(b2f(v3[i]), w3, acc[i]);
    }
    if (j + 2 <= e) {
        int c0 = col[j], c1 = col[j + 1];
        float w0 = w[j], w1 = w[j + 1];
        u16x8 v0 = *(const u16x8*)&X[(long)c0 * 1024 + elem];
        u16x8 v1 = *(const u16x8*)&X[(long)c1 * 1024 + elem];
        #pragma unroll
        for (int i = 0; i < 8; ++i) acc[i] = fmaf(b2f(v0[i]), w0, acc[i]);
        #pragma unroll
        for (int i = 0; i < 8; ++i) acc[i] = fmaf(b2f(v1[i]), w1, acc[i]);
        j += 2;
    }
    if (j < e) {
        int c = col[j];
        float ww = w[j];
        u16x8 v = *(const u16x8*)&X[(long)c * 1024 + elem];
        #pragma unroll
        for (int i = 0; i < 8; ++i) acc[i] = fmaf(b2f(v[i]), ww, acc[i]);
    }
    long o = (long)n * 1024 + elem;
    #pragma unroll
    for (int i = 0; i < 8; ++i) acc[i] *= alpha;
    if (beta != 0.f) {
        u16x8 bb = *(const u16x8*)&base[o];
        #pragma unroll
        for (int i = 0; i < 8; ++i) acc[i] = fmaf(beta, b2f(bb[i]), acc[i]);
    }
    u16x8 r;
    #pragma unroll
    for (int i = 0; i < 8; ++i) r[i] = f2b(acc[i]);
    *(u16x8*)&out[o] = r;
}

// ---------------- MFMA 10-term GEMMs (stride-128 X rows), register-pipelined ----------------
struct GM {
    const ushort* X[10];    // pre-offset by chunk*64; row stride 128
    const ushort* Wa[10];   // pre-offset by chunk*64; row stride 128
    const ushort* Wb[10];
};

#define LOADF(tt, aa, bb)                                                          \
    {                                                                              \
        const ushort* Xp = A.X[tt];                                                \
        const ushort* Wp = gate ? A.Wb[tt] : A.Wa[tt];                             \
        _Pragma("unroll")                                                          \
        for (int ks = 0; ks < 2; ++ks) {                                           \
            _Pragma("unroll")                                                      \
            for (int mi = 0; mi < 2; ++mi)                                         \
                aa[ks][mi] = *(const bf16x8*)&Xp[(grow + mi * 16 + lr) * 128 +     \
                                                 ks * 32 + lk * 8];                \
            _Pragma("unroll")                                                      \
            for (int ni = 0; ni < 4; ++ni)                                         \
                bb[ks][ni] = *(const bf16x8*)&Wp[(ni * 16 + lr) * 128 +            \
                                                 ks * 32 + lk * 8];                \
        }                                                                          \
    }

#define MFMAF(aa, bb)                                                              \
    _Pragma("unroll")                                                              \
    for (int ks = 0; ks < 2; ++ks)                                                 \
        _Pragma("unroll")                                                          \
        for (int mi = 0; mi < 2; ++mi)                                             \
            _Pragma("unroll")                                                      \
            for (int ni = 0; ni < 4; ++ni)                                         \
                acc[mi][ni] = __builtin_amdgcn_mfma_f32_16x16x32_bf16(             \
                    aa[ks][mi], bb[ks][ni], acc[mi][ni], 0, 0, 0);

// dual gate: 64 rows/block, 4 waves (gate x 32-row half)
// launch_bounds min-waves=4 -> VGPR budget 128 so BOTH pipeline stages stay live
template<int NT>
__global__ __launch_bounds__(256, 4) void mfma_dual(GM A,
        const float* __restrict__ bzp, const float* __restrict__ brp,
        const float* __restrict__ h,
        float* __restrict__ Z, ushort* __restrict__ xh) {
    int lane = threadIdx.x & 63;
    int wid  = threadIdx.x >> 6;
    int gate = wid >> 1;
    long grow = (long)blockIdx.x * 64 + (long)(wid & 1) * 32;
    int lr = lane & 15;
    int lk = lane >> 4;
    f32x4 acc[2][4];
    #pragma unroll
    for (int i = 0; i < 2; ++i)
        #pragma unroll
        for (int j = 0; j < 4; ++j)
            acc[i][j] = (f32x4){0.f, 0.f, 0.f, 0.f};

    bf16x8 a0[2][2], b0[2][4], a1[2][2], b1[2][4];
    LOADF(0, a0, b0);
    #pragma unroll
    for (int tt = 0; tt < NT; tt += 2) {
        if (tt + 1 < NT) LOADF(tt + 1, a1, b1);
        MFMAF(a0, b0);
        if (tt + 2 < NT) LOADF(tt + 2, a0, b0);
        if (tt + 1 < NT) MFMAF(a1, b1);
    }

    const float* bias = gate ? brp : bzp;
    #pragma unroll
    for (int mi = 0; mi < 2; ++mi) {
        #pragma unroll
        for (int q = 0; q < 4; ++q) {
            long row = grow + mi * 16 + lk * 4 + q;
            int n = (int)(row >> 3), b = (int)(row & 7);
            #pragma unroll
            for (int ni = 0; ni < 4; ++ni) {
                int colc = ni * 16 + lr;
                float v = acc[mi][ni][q] + bias[colc];
                float sg = 1.f / (1.f + expf(-v));
                if (gate == 0) {
                    Z[row * 64 + colc] = sg;
                } else {
                    float hv = h[((long)b * NN + n) * 64 + colc];
                    xh[row * 128 + 64 + colc] = f2b(sg * hv);
                }
            }
        }
    }
}

// single gate (H): 64 rows/block, 2 waves; fused GRU blend epilogue
template<int NT>
__global__ __launch_bounds__(128, 4) void mfma_single(GM A,
        const float* __restrict__ bhp, const float* __restrict__ h,
        const float* __restrict__ Zg,
        float* __restrict__ outF, ushort* __restrict__ xh, int writeF) {
    int lane = threadIdx.x & 63;
    int wid  = threadIdx.x >> 6;
    const int gate = 0;
    long grow = (long)blockIdx.x * 64 + (long)wid * 32;
    int lr = lane & 15;
    int lk = lane >> 4;
    f32x4 acc[2][4];
    #pragma unroll
    for (int i = 0; i < 2; ++i)
        #pragma unroll
        for (int j = 0; j < 4; ++j)
            acc[i][j] = (f32x4){0.f, 0.f, 0.f, 0.f};

    bf16x8 a0[2][2], b0[2][4], a1[2][2], b1[2][4];
    LOADF(0, a0, b0);
    #pragma unroll
    for (int tt = 0; tt < NT; tt += 2) {
        if (tt + 1 < NT) LOADF(tt + 1, a1, b1);
        MFMAF(a0, b0);
        if (tt + 2 < NT) LOADF(tt + 2, a0, b0);
        if (tt + 1 < NT) MFMAF(a1, b1);
    }

    #pragma unroll
    for (int mi = 0; mi < 2; ++mi) {
        #pragma unroll
        for (int q = 0; q < 4; ++q) {
            long row = grow + mi * 16 + lk * 4 + q;
            int n = (int)(row >> 3), b = (int)(row & 7);
            #pragma unroll
            for (int ni = 0; ni < 4; ++ni) {
                int colc = ni * 16 + lr;
                float v = acc[mi][ni][q] + bhp[colc];
                float ht = tanhf(v);
                float z = Zg[row * 64 + colc];
                float hv = h[((long)b * NN + n) * 64 + colc];
                float res = z * hv + (1.f - z) * ht;
                if (writeF) outF[row * 64 + colc] = res;
                else        xh[row * 128 + colc] = f2b(res);
            }
        }
    }
}

// ---------------- final projection 64 -> 32 (permuted input rows) ----------------
__global__ void proj_kernel(const float* __restrict__ last, const float* __restrict__ W,
                            const float* __restrict__ bias, float* __restrict__ out) {
    long t = (long)blockIdx.x * blockDim.x + threadIdx.x;
    if (t >= (long)ROWS * OUTD) return;
    long row = t >> 5;              // n*8 + b
    int  o   = (int)(t & 31);
    int n = (int)(row >> 3), b = (int)(row & 7);
    float acc = bias[o];
    #pragma unroll
    for (int hh = 0; hh < HIDD; ++hh)
        acc = fmaf(last[row * 64 + hh], W[hh * OUTD + o], acc);
    out[((long)b * NN + n) * 32 + o] = acc;
}

extern "C" void kernel_launch(void* const* d_in, const int* in_sizes, int n_in,
                              void* d_out, int out_size, void* d_ws, size_t ws_size,
                              hipStream_t stream) {
    const float* edge_weight = (const float*)d_in[0];
    const float* hidden      = (const float*)d_in[1];
    const float* go_input    = (const float*)d_in[2];
    const float* Wz = (const float*)d_in[3];
    const float* bz = (const float*)d_in[4];
    const float* Wr = (const float*)d_in[5];
    const float* br = (const float*)d_in[6];
    const float* Wh = (const float*)d_in[7];
    const float* bh = (const float*)d_in[8];
    const float* projW = (const float*)d_in[9];
    const float* projb = (const float*)d_in[10];
    const int*   eidx  = (const int*)d_in[11];
    const int* src = eidx;
    const int* dst = eidx + NE;
    float* out = (float*)d_out;

    // ---- workspace ----
    char* p = (char*)d_ws;
    auto alloc = [&](size_t bytes) { char* r = p; p += (bytes + 15) & ~(size_t)15; return r; };
    float* deg_out = (float*)alloc(NN * 4);
    float* deg_in  = (float*)alloc(NN * 4);
    int*   cnt_f   = (int*)alloc(NN * 4);
    int*   cnt_r   = (int*)alloc(NN * 4);
    int*   off_f   = (int*)alloc((NN + 4) * 4);
    int*   off_r   = (int*)alloc((NN + 4) * 4);
    int*   pos_f   = (int*)alloc(NN * 4);
    int*   pos_r   = (int*)alloc(NN * 4);
    int*   col_f   = (int*)alloc(NE * 4);
    float* w_f     = (float*)alloc(NE * 4);
    int*   col_r   = (int*)alloc(NE * 4);
    float* w_r     = (float*)alloc(NE * 4);
    ushort* Wt     = (ushort*)alloc((size_t)2 * 3 * 2 * 3 * 64 * 128 * 2);
    const size_t XB = (size_t)ROWS * 128 * 2;   // 20.48 MB (128-wide bf16)
    ushort* xh  = (ushort*)alloc(XB);
    ushort* Tf1 = (ushort*)alloc(XB);
    ushort* Tf2 = (ushort*)alloc(XB);
    ushort* Tr1 = (ushort*)alloc(XB);
    ushort* Tr2 = (ushort*)alloc(XB);
    float*  Zbuf = (float*)alloc((size_t)ROWS * HIDD * 4);
    if ((size_t)(p - (char*)d_ws) > ws_size) return;

    const int TB = 256;
    const int EGRID = (NE + TB - 1) / TB;
    const dim3 PG(NN, 2);

    // ---- CSR build ----
    zero_kernel<<<(4 * NN + TB - 1) / TB, TB, 0, stream>>>((int*)deg_out, 4 * NN);
    deg_cnt_kernel<<<EGRID, TB, 0, stream>>>(edge_weight, src, dst, deg_out, deg_in, cnt_f, cnt_r);
    scan_kernel<<<1, 256, 0, stream>>>(cnt_f, off_f);
    scan_kernel<<<1, 256, 0, stream>>>(cnt_r, off_r);
    copy_pos_kernel<<<(NN + TB - 1) / TB, TB, 0, stream>>>(off_f, off_r, pos_f, pos_r);
    fill_kernel<<<EGRID, TB, 0, stream>>>(edge_weight, src, dst, deg_out, deg_in,
                                          pos_f, pos_r, col_f, w_f, col_r, w_r);

    convW_kernel<<<2304, 256, 0, stream>>>(Wz, Wr, Wh, Wt);
    convX_perm<<<5000, 256, 0, stream>>>((const float4*)go_input, xh, 0);

    auto wt_term = [&](int l, int g, int d, int k, int c) -> const ushort* {
        return Wt + ((((long)((l * 3 + g) * 2 + d) * 3 + k) * 64) * 128) + (long)c * 64;
    };
    const int dd[5]  = {0, 0, 0, 1, 1};
    const int kk2[5] = {0, 1, 2, 1, 2};

    for (int l = 0; l < NL; ++l) {
        const float* h = hidden + (long)l * ROWS * HIDD;
        convX_perm<<<5000, 256, 0, stream>>>((const float4*)h, xh, 1);

        // xh diffusion (both chunks at once, fwd+rev via blockIdx.y)
        prop_full<<<PG, 128, 0, stream>>>(xh, xh, nullptr,
            off_f, col_f, w_f, off_r, col_r, w_r, Tf1, Tr1, 1.f, 0.f);
        prop_full<<<PG, 128, 0, stream>>>(Tf1, Tr1, xh,
            off_f, col_f, w_f, off_r, col_r, w_r, Tf2, Tr2, 2.f, -1.f);

        const ushort* xs[5] = {xh, Tf1, Tf2, Tr1, Tr2};
        GM A{};
        for (int i = 0; i < 5; ++i) {
            A.X[i]      = xs[i];
            A.X[5 + i]  = xs[i] + 64;
            A.Wa[i]     = wt_term(l, 0, dd[i], kk2[i], 0);
            A.Wa[5 + i] = wt_term(l, 0, dd[i], kk2[i], 1);
            A.Wb[i]     = wt_term(l, 1, dd[i], kk2[i], 0);
            A.Wb[5 + i] = wt_term(l, 1, dd[i], kk2[i], 1);
        }
        mfma_dual<10><<<ROWS / 64, 256, 0, stream>>>(A, bz + l * HIDD, br + l * HIDD,
                                                     h, Zbuf, xh);

        // rh diffusion into the chunk-1 halves (rh lives in xh chunk1)
        prop_half<<<PG, 64, 0, stream>>>(xh, xh, nullptr,
            off_f, col_f, w_f, off_r, col_r, w_r, Tf1, Tr1, 1.f, 0.f);
        prop_half<<<PG, 64, 0, stream>>>(Tf1, Tr1, xh,
            off_f, col_f, w_f, off_r, col_r, w_r, Tf2, Tr2, 2.f, -1.f);

        GM Ah{};
        for (int i = 0; i < 5; ++i) {
            Ah.X[i]      = xs[i];
            Ah.X[5 + i]  = xs[i] + 64;
            Ah.Wa[i]     = wt_term(l, 2, dd[i], kk2[i], 0);
            Ah.Wa[5 + i] = wt_term(l, 2, dd[i], kk2[i], 1);
        }
        mfma_single<10><<<ROWS / 64, 128, 0, stream>>>(Ah, bh + l * HIDD, h, Zbuf,
                                                       Zbuf, xh, (l == NL - 1) ? 1 : 0);
    }

    proj_kernel<<<(int)(((long)ROWS * OUTD + TB - 1) / TB), TB, 0, stream>>>(
        Zbuf, projW, projb, out);
}